// Round 1
// 100.880 us; speedup vs baseline: 1.1339x; 1.1339x over previous
//
#include <hip/hip_runtime.h>

// TensorTree collapsed to multilinear table: out[b,u] = w1(b)^T T_u w2(b),
// w1 = x0(x)x1(x)x2(x)x3, w2 = x4(x)x5(x)x6(x)x7  (16-dim each).
// Round 4:
//  - precompute_T_fast: all six cores + MT staged into LDS with coalesced
//    loads (phases A/B were latency-bound on scattered global core reads
//    with only 32 blocks on chip); FMA chains split 2-way for ILP.
//  - tree_eval: __launch_bounds__(256,4) -> 128-VGPR budget. Round-3 binary
//    allocated only 64 arch VGPRs for >=80 live floats (w1/w2 parked in
//    AGPRs / reloaded per use inside the 16x16 loop) -> VALUBusy 28.5%.
//    With 128 VGPRs the ~90-float working set is register-resident at
//    4 waves/SIMD.

#define BB 65536
#define FF 8
#define DD 2
#define RR 10
#define UU 32
#define UPT 2
#define BPT 2

// ---------------- kernel 1: precompute T (one block per unit) ----------------

__global__ __launch_bounds__(256) void precompute_T_fast(
    const float* __restrict__ core11, const float* __restrict__ core12,
    const float* __restrict__ core13, const float* __restrict__ core14,
    const float* __restrict__ core21, const float* __restrict__ core22,
    const float* __restrict__ FM, const float* __restrict__ MT,
    float* __restrict__ T)
{
    const int u   = blockIdx.x;    // 0..31
    const int tid = threadIdx.x;   // 0..255

    __shared__ float sC[6][RR * RR * RR];  // staged cores, 24 KB
    __shared__ float sMT[RR * RR];
    __shared__ float sLeaf[FF][2][RR];   // [leaf][basis][r]
    __shared__ float sP[4][4][RR];       // [pair][combo(a_lo + 2*a_hi)][j]
    __shared__ float sQ[2][16][RR];      // [side][combo][j]
    __shared__ float sR1[16][RR];        // Q1 . MT

    // Phase -1: stage cores + MT into LDS, coalesced (4 rounds x 6 arrays).
#pragma unroll
    for (int r = 0; r < 4; ++r) {
        const int o = tid + 256 * r;
        if (o < RR * RR * RR) {
            sC[0][o] = core11[o];
            sC[1][o] = core12[o];
            sC[2][o] = core13[o];
            sC[3][o] = core14[o];
            sC[4][o] = core21[o];
            sC[5][o] = core22[o];
        }
    }
    if (tid < RR * RR) sMT[tid] = MT[tid];

    // Phase 0: leaf basis vectors. leaf[f][a][r] = FM[a, r, f, u]
    if (tid < FF * 2 * RR) {             // 160 tasks
        const int f = tid / (2 * RR);
        const int rem = tid % (2 * RR);
        const int a = rem / RR;
        const int r = rem % RR;
        sLeaf[f][a][r] = FM[((a * RR + r) * FF + f) * UU + u];
    }
    __syncthreads();

    // Phase A: level-1 pairs. 4 pairs x 4 combos x RR j = 160 tasks.
    if (tid < 4 * 4 * RR) {
        const int P   = tid / (4 * RR);        // which pair
        const int rem = tid % (4 * RR);
        const int s   = rem / RR;              // combo: a_lo + 2*a_hi
        const int j   = rem % RR;
        const int fa = 2 * P, fb = 2 * P + 1;
        const int ai = s & 1, bi = s >> 1;
        const float* cp = sC[P];
        float a[RR], b[RR];
#pragma unroll
        for (int i = 0; i < RR; ++i) { a[i] = sLeaf[fa][ai][i]; b[i] = sLeaf[fb][bi][i]; }
        float acc0 = 0.0f, acc1 = 0.0f;
#pragma unroll
        for (int i = 0; i < RR; ++i) {
#pragma unroll
            for (int k = 0; k < RR; ++k) {
                const float w = a[i] * b[k];
                const float c = cp[(i * RR + k) * RR + j];
                if (i & 1) acc1 = fmaf(w, c, acc1);
                else       acc0 = fmaf(w, c, acc0);
            }
        }
        sP[P][s][j] = acc0 + acc1;
    }
    __syncthreads();

    // Phase B: level-2. 2 sides x 16 combos x RR j = 320 tasks.
    for (int t = tid; t < 2 * 16 * RR; t += 256) {
        const int side  = t / (16 * RR);
        const int rem   = t % (16 * RR);
        const int combo = rem / RR;
        const int j     = rem % RR;
        const int pa = side * 2, pb = side * 2 + 1;     // P1,P2 or P3,P4
        const float* cp = sC[4 + side];
        float a[RR], b[RR];
#pragma unroll
        for (int i = 0; i < RR; ++i) {
            a[i] = sP[pa][combo & 3][i];
            b[i] = sP[pb][combo >> 2][i];
        }
        float acc0 = 0.0f, acc1 = 0.0f;
#pragma unroll
        for (int i = 0; i < RR; ++i) {
#pragma unroll
            for (int k = 0; k < RR; ++k) {
                const float w = a[i] * b[k];
                const float c = cp[(i * RR + k) * RR + j];
                if (i & 1) acc1 = fmaf(w, c, acc1);
                else       acc0 = fmaf(w, c, acc0);
            }
        }
        sQ[side][combo][j] = acc0 + acc1;
    }
    __syncthreads();

    // Phase C: R1[p][j] = sum_i Q1[p][i] * MT[i][j]. 160 tasks.
    if (tid < 16 * RR) {
        const int p = tid / RR;
        const int j = tid % RR;
        float acc = 0.0f;
#pragma unroll
        for (int i = 0; i < RR; ++i)
            acc = fmaf(sQ[0][p][i], sMT[i * RR + j], acc);
        sR1[p][j] = acc;
    }
    __syncthreads();

    // Phase D: T[u][q*16+p] = sum_j R1[p][j] * Q2[q][j]. 256 tasks.
    {
        const int c = tid;
        const int p = c & 15, q = c >> 4;
        float acc = 0.0f;
#pragma unroll
        for (int j = 0; j < RR; ++j)
            acc = fmaf(sR1[p][j], sQ[1][q][j], acc);
        T[u * 256 + c] = acc;
    }
}

// ---------------- kernel 2: batch evaluation ----------------

__global__ __launch_bounds__(256, 4) void tree_eval(
    const float* __restrict__ X,
    const float* __restrict__ T,
    float* __restrict__ out)
{
    const int b0 = blockIdx.x * blockDim.x + threadIdx.x;  // 0..32767
    const int u0 = blockIdx.y * UPT;                       // block-uniform

    const float* __restrict__ Ta = T + (u0 + 0) * 256;     // wave-uniform
    const float* __restrict__ Tb = T + (u0 + 1) * 256;

    float w1[BPT][16], w2[BPT][16];
#pragma unroll
    for (int bt = 0; bt < BPT; ++bt) {
        const int b = b0 + bt * (BB / BPT);
        const float4* xp = reinterpret_cast<const float4*>(X + (size_t)b * (FF * DD));
        // build w1 with minimal live range: t01/t23 die before t45/t67 load
        float4 v0 = xp[0];
        float4 v1 = xp[1];
        float t01[4], t23[4];
#pragma unroll
        for (int a1 = 0; a1 < 2; ++a1)
#pragma unroll
            for (int a0 = 0; a0 < 2; ++a0) {
                const float xa0 = (a0 == 0) ? v0.x : v0.y;   // x[0][a0]
                const float xa1 = (a1 == 0) ? v0.z : v0.w;   // x[1][a1]
                const float xb0 = (a0 == 0) ? v1.x : v1.y;   // x[2][a0]
                const float xb1 = (a1 == 0) ? v1.z : v1.w;   // x[3][a1]
                t01[a1 * 2 + a0] = xa0 * xa1;
                t23[a1 * 2 + a0] = xb0 * xb1;
            }
#pragma unroll
        for (int p = 0; p < 16; ++p)
            w1[bt][p] = t01[p & 3] * t23[p >> 2];

        float4 v2 = xp[2];
        float4 v3 = xp[3];
        float t45[4], t67[4];
#pragma unroll
        for (int a1 = 0; a1 < 2; ++a1)
#pragma unroll
            for (int a0 = 0; a0 < 2; ++a0) {
                const float xa0 = (a0 == 0) ? v2.x : v2.y;   // x[4][a0]
                const float xa1 = (a1 == 0) ? v2.z : v2.w;   // x[5][a1]
                const float xb0 = (a0 == 0) ? v3.x : v3.y;   // x[6][a0]
                const float xb1 = (a1 == 0) ? v3.z : v3.w;   // x[7][a1]
                t45[a1 * 2 + a0] = xa0 * xa1;
                t67[a1 * 2 + a0] = xb0 * xb1;
            }
#pragma unroll
        for (int p = 0; p < 16; ++p)
            w2[bt][p] = t45[p & 3] * t67[p >> 2];
    }

    float accA[BPT], accB[BPT];
#pragma unroll
    for (int bt = 0; bt < BPT; ++bt) { accA[bt] = 0.0f; accB[bt] = 0.0f; }

#pragma unroll
    for (int q = 0; q < 16; ++q) {
        float sA[BPT], sB[BPT];
#pragma unroll
        for (int bt = 0; bt < BPT; ++bt) { sA[bt] = 0.0f; sB[bt] = 0.0f; }
#pragma unroll
        for (int p = 0; p < 16; ++p) {
            const float ta = Ta[q * 16 + p];   // scalar (u0 uniform) -> s_load
            const float tb = Tb[q * 16 + p];
#pragma unroll
            for (int bt = 0; bt < BPT; ++bt) {
                sA[bt] = fmaf(ta, w1[bt][p], sA[bt]);
                sB[bt] = fmaf(tb, w1[bt][p], sB[bt]);
            }
        }
#pragma unroll
        for (int bt = 0; bt < BPT; ++bt) {
            accA[bt] = fmaf(w2[bt][q], sA[bt], accA[bt]);
            accB[bt] = fmaf(w2[bt][q], sB[bt], accB[bt]);
        }
    }

#pragma unroll
    for (int bt = 0; bt < BPT; ++bt) {
        const int b = b0 + bt * (BB / BPT);
        float2 o;
        o.x = accA[bt];
        o.y = accB[bt];
        *reinterpret_cast<float2*>(out + (size_t)b * UU + u0) = o;
    }
}

extern "C" void kernel_launch(void* const* d_in, const int* in_sizes, int n_in,
                              void* d_out, int out_size, void* d_ws, size_t ws_size,
                              hipStream_t stream) {
    const float* X      = (const float*)d_in[0];
    const float* core11 = (const float*)d_in[1];
    const float* core12 = (const float*)d_in[2];
    const float* core13 = (const float*)d_in[3];
    const float* core14 = (const float*)d_in[4];
    const float* core21 = (const float*)d_in[5];
    const float* core22 = (const float*)d_in[6];
    const float* FM     = (const float*)d_in[7];
    const float* MT     = (const float*)d_in[8];
    float* out          = (float*)d_out;
    float* T            = (float*)d_ws;   // 32*256*4 = 32 KB

    precompute_T_fast<<<dim3(UU), dim3(256), 0, stream>>>(
        core11, core12, core13, core14, core21, core22, FM, MT, T);

    tree_eval<<<dim3(BB / (256 * BPT), UU / UPT), dim3(256), 0, stream>>>(X, T, out);
}

// Round 3
// 93.550 us; speedup vs baseline: 1.2227x; 1.0784x over previous
//
#include <hip/hip_runtime.h>

// TensorTree collapsed to multilinear table: out[b,u] = w1(b)^T T_u w2(b),
// w1 = t01(x)t23, w2 = t45(x)t67  (16-dim each), i.e.
//   out[b,u] = sum_c K[b][c] * T[u][c],  c = q*16+p,  K[c] = w1[p]*w2[q]
// Round 6 (= round-5 MFMA design, toolchain-hardened):
//  - no __bf16 anywhere: bf16 pack/unpack via integer bit ops (truncation
//    hi/lo split; the residual term makes the split self-correcting, total
//    rep error ~2^-16).
//  - MFMA frags are ext_vector(8) short — the guide's compile-verified form.
//  - tree_eval: T panel consumed as MFMA B-operand (L1-resident 32 KB),
//    A-frags built per lane from its own X load, no LDS, no barriers.
//    K-index algebra: c = s*32 + kb*8 + j  ->  q = 2s+(kb>>1), p=(kb&1)*8+j.
//  - precision: K = ah+al, T = Thi+Tlo, 3 MFMA products (drop al*bl ~2^-16).

#define BB 65536
#define FF 8
#define DD 2
#define RR 10
#define UU 32

typedef __attribute__((ext_vector_type(8))) short short8;
typedef __attribute__((ext_vector_type(4))) float f32x4;

__device__ __forceinline__ unsigned short f2bf_trunc(float x) {
    return (unsigned short)(__builtin_bit_cast(unsigned int, x) >> 16);
}
__device__ __forceinline__ float bf2f(unsigned short h) {
    return __builtin_bit_cast(float, ((unsigned int)h) << 16);
}

// ---------------- kernel 1: precompute T (one block per unit) ----------------

__global__ __launch_bounds__(256) void precompute_T_fast(
    const float* __restrict__ core11, const float* __restrict__ core12,
    const float* __restrict__ core13, const float* __restrict__ core14,
    const float* __restrict__ core21, const float* __restrict__ core22,
    const float* __restrict__ FM, const float* __restrict__ MT,
    unsigned short* __restrict__ Thi, unsigned short* __restrict__ Tlo)
{
    const int u   = blockIdx.x;    // 0..31
    const int tid = threadIdx.x;   // 0..255

    __shared__ float sC[6][RR * RR * RR];  // staged cores, 24 KB
    __shared__ float sMT[RR * RR];
    __shared__ float sLeaf[FF][2][RR];   // [leaf][basis][r]
    __shared__ float sP[4][4][RR];       // [pair][combo(a_lo + 2*a_hi)][j]
    __shared__ float sQ[2][16][RR];      // [side][combo][j]
    __shared__ float sR1[16][RR];        // Q1 . MT

    // Phase -1: stage cores + MT into LDS, coalesced.
#pragma unroll
    for (int r = 0; r < 4; ++r) {
        const int o = tid + 256 * r;
        if (o < RR * RR * RR) {
            sC[0][o] = core11[o];
            sC[1][o] = core12[o];
            sC[2][o] = core13[o];
            sC[3][o] = core14[o];
            sC[4][o] = core21[o];
            sC[5][o] = core22[o];
        }
    }
    if (tid < RR * RR) sMT[tid] = MT[tid];

    // Phase 0: leaf basis vectors. leaf[f][a][r] = FM[a, r, f, u]
    if (tid < FF * 2 * RR) {             // 160 tasks
        const int f = tid / (2 * RR);
        const int rem = tid % (2 * RR);
        const int a = rem / RR;
        const int r = rem % RR;
        sLeaf[f][a][r] = FM[((a * RR + r) * FF + f) * UU + u];
    }
    __syncthreads();

    // Phase A: level-1 pairs. 4 pairs x 4 combos x RR j = 160 tasks.
    if (tid < 4 * 4 * RR) {
        const int P   = tid / (4 * RR);
        const int rem = tid % (4 * RR);
        const int s   = rem / RR;              // combo: a_lo + 2*a_hi
        const int j   = rem % RR;
        const int fa = 2 * P, fb = 2 * P + 1;
        const int ai = s & 1, bi = s >> 1;
        const float* cp = sC[P];
        float a[RR], b[RR];
#pragma unroll
        for (int i = 0; i < RR; ++i) { a[i] = sLeaf[fa][ai][i]; b[i] = sLeaf[fb][bi][i]; }
        float acc0 = 0.0f, acc1 = 0.0f;
#pragma unroll
        for (int i = 0; i < RR; ++i) {
#pragma unroll
            for (int k = 0; k < RR; ++k) {
                const float w = a[i] * b[k];
                const float c = cp[(i * RR + k) * RR + j];
                if (i & 1) acc1 = fmaf(w, c, acc1);
                else       acc0 = fmaf(w, c, acc0);
            }
        }
        sP[P][s][j] = acc0 + acc1;
    }
    __syncthreads();

    // Phase B: level-2. 2 sides x 16 combos x RR j = 320 tasks.
    for (int t = tid; t < 2 * 16 * RR; t += 256) {
        const int side  = t / (16 * RR);
        const int rem   = t % (16 * RR);
        const int combo = rem / RR;
        const int j     = rem % RR;
        const int pa = side * 2, pb = side * 2 + 1;
        const float* cp = sC[4 + side];
        float a[RR], b[RR];
#pragma unroll
        for (int i = 0; i < RR; ++i) {
            a[i] = sP[pa][combo & 3][i];
            b[i] = sP[pb][combo >> 2][i];
        }
        float acc0 = 0.0f, acc1 = 0.0f;
#pragma unroll
        for (int i = 0; i < RR; ++i) {
#pragma unroll
            for (int k = 0; k < RR; ++k) {
                const float w = a[i] * b[k];
                const float c = cp[(i * RR + k) * RR + j];
                if (i & 1) acc1 = fmaf(w, c, acc1);
                else       acc0 = fmaf(w, c, acc0);
            }
        }
        sQ[side][combo][j] = acc0 + acc1;
    }
    __syncthreads();

    // Phase C: R1[p][j] = sum_i Q1[p][i] * MT[i][j]. 160 tasks.
    if (tid < 16 * RR) {
        const int p = tid / RR;
        const int j = tid % RR;
        float acc = 0.0f;
#pragma unroll
        for (int i = 0; i < RR; ++i)
            acc = fmaf(sQ[0][p][i], sMT[i * RR + j], acc);
        sR1[p][j] = acc;
    }
    __syncthreads();

    // Phase D: T[u][c=q*16+p] = sum_j R1[p][j]*Q2[q][j]; emit bf16 hi/lo split.
    {
        const int c = tid;
        const int p = c & 15, q = c >> 4;
        float acc = 0.0f;
#pragma unroll
        for (int j = 0; j < RR; ++j)
            acc = fmaf(sR1[p][j], sQ[1][q][j], acc);
        const unsigned short h = f2bf_trunc(acc);
        const unsigned short l = f2bf_trunc(acc - bf2f(h));
        Thi[u * 256 + c] = h;
        Tlo[u * 256 + c] = l;
    }
}

// ---------------- kernel 2: batch evaluation via MFMA ----------------
// grid = (512, 2), block = 256 (4 waves). Each wave: 16 units (ubase +
// lane&15 column), 2 iterations x 16 batches. mfma_f32_16x16x32_bf16,
// D: row=(lane>>4)*4+reg -> batch, col=lane&15 -> unit (verified layout).

#define NWAVE 2048   // waves per unit-group = gridDim.x * 4

__global__ __launch_bounds__(256, 4) void tree_eval_mfma(
    const float* __restrict__ X,
    const unsigned short* __restrict__ Thi,
    const unsigned short* __restrict__ Tlo,
    float* __restrict__ out)
{
    const int lane  = threadIdx.x & 63;
    const int wid   = threadIdx.x >> 6;                 // 0..3
    const int gw    = blockIdx.x * 4 + wid;             // 0..NWAVE-1
    const int ubase = blockIdx.y * 16;

    const int n  = lane & 15;    // unit column / batch row owner
    const int kb = lane >> 4;    // k-block 0..3

    // B-operand base: lane holds T[ubase+n][s*32 + kb*8 + j], j=0..7.
    const unsigned short* th = Thi + (ubase + n) * 256 + kb * 8;
    const unsigned short* tl = Tlo + (ubase + n) * 256 + kb * 8;

    const int qpar = kb >> 1;    // parity of w2 index this lane consumes
    const int kpar = kb & 1;     // which half of w1 this lane consumes

#pragma unroll
    for (int it = 0; it < 2; ++it) {
        const int bbase = (it * NWAVE + gw) * 16;

        // ---- per-lane w build (batch bbase+n; shared across kb groups) ----
        const float* xp = X + (size_t)(bbase + n) * (FF * DD);
        const float4 v0 = *reinterpret_cast<const float4*>(xp + 0);
        const float4 v1 = *reinterpret_cast<const float4*>(xp + 4);
        const float4 v2 = *reinterpret_cast<const float4*>(xp + 8);
        const float4 v3 = *reinterpret_cast<const float4*>(xp + 12);

        float t01[4], t23[4], t45[4], t67[4];
        t01[0] = v0.x * v0.z; t01[1] = v0.y * v0.z; t01[2] = v0.x * v0.w; t01[3] = v0.y * v0.w;
        t23[0] = v1.x * v1.z; t23[1] = v1.y * v1.z; t23[2] = v1.x * v1.w; t23[3] = v1.y * v1.w;
        t45[0] = v2.x * v2.z; t45[1] = v2.y * v2.z; t45[2] = v2.x * v2.w; t45[3] = v2.y * v2.w;
        t67[0] = v3.x * v3.z; t67[1] = v3.y * v3.z; t67[2] = v3.x * v3.w; t67[3] = v3.y * v3.w;

        // w1[p], p = kpar*8+j: w1[p] = t01[j&3] * t23[2*kpar + (j>>2)]
        const float v23_0 = kpar ? t23[2] : t23[0];
        const float v23_1 = kpar ? t23[3] : t23[1];
        float w1own[8];
#pragma unroll
        for (int j = 0; j < 8; ++j)
            w1own[j] = t01[j & 3] * ((j >> 2) ? v23_1 : v23_0);

        // w2[q], q = 2s+qpar: w2[q] = t45[2*(s&1)+qpar] * t67[s>>1]
        const float u45_0 = qpar ? t45[1] : t45[0];
        const float u45_1 = qpar ? t45[3] : t45[2];

        f32x4 acc = {0.0f, 0.0f, 0.0f, 0.0f};

#pragma unroll
        for (int s = 0; s < 8; ++s) {
            const float w2s = ((s & 1) ? u45_1 : u45_0) * t67[s >> 1];

            short8 ah, al;
#pragma unroll
            for (int j = 0; j < 8; ++j) {
                const float a = w1own[j] * w2s;
                const unsigned short h = f2bf_trunc(a);
                ah[j] = (short)h;
                al[j] = (short)f2bf_trunc(a - bf2f(h));
            }
            const short8 bh = *reinterpret_cast<const short8*>(th + s * 32);
            const short8 bl = *reinterpret_cast<const short8*>(tl + s * 32);

            acc = __builtin_amdgcn_mfma_f32_16x16x32_bf16(ah, bh, acc, 0, 0, 0);
            acc = __builtin_amdgcn_mfma_f32_16x16x32_bf16(al, bh, acc, 0, 0, 0);
            acc = __builtin_amdgcn_mfma_f32_16x16x32_bf16(ah, bl, acc, 0, 0, 0);
        }

        // D: batch = bbase + kb*4 + r, unit = ubase + n
        float* op = out + (size_t)(bbase + kb * 4) * UU + ubase + n;
#pragma unroll
        for (int r = 0; r < 4; ++r)
            op[(size_t)r * UU] = acc[r];
    }
}

extern "C" void kernel_launch(void* const* d_in, const int* in_sizes, int n_in,
                              void* d_out, int out_size, void* d_ws, size_t ws_size,
                              hipStream_t stream) {
    const float* X      = (const float*)d_in[0];
    const float* core11 = (const float*)d_in[1];
    const float* core12 = (const float*)d_in[2];
    const float* core13 = (const float*)d_in[3];
    const float* core14 = (const float*)d_in[4];
    const float* core21 = (const float*)d_in[5];
    const float* core22 = (const float*)d_in[6];
    const float* FM     = (const float*)d_in[7];
    const float* MT     = (const float*)d_in[8];
    float* out          = (float*)d_out;

    unsigned short* Thi = (unsigned short*)d_ws;          // 32*256*2 = 16 KB
    unsigned short* Tlo = Thi + UU * 256;                 // +16 KB

    precompute_T_fast<<<dim3(UU), dim3(256), 0, stream>>>(
        core11, core12, core13, core14, core21, core22, FM, MT, Thi, Tlo);

    tree_eval_mfma<<<dim3(512, 2), dim3(256), 0, stream>>>(X, Thi, Tlo, out);
}

// Round 4
// 88.402 us; speedup vs baseline: 1.2939x; 1.0582x over previous
//
#include <hip/hip_runtime.h>

// TensorTree collapsed to multilinear table: out[b,u] = w1(b)^T T_u w2(b),
//   out[b,u] = sum_c K[b][c] * T[u][c],  c = q*16+p,  K[c] = w1[p]*w2[q]
// Round 7: de-latency the MFMA eval kernel. Round-6 ran ~21 us (vs ~5 us
// VALU model) -> latency-bound:
//  - B-frags (T panel) hoisted to registers ONCE per wave (they are
//    it-loop invariant): zero VMEM + zero vmcnt stalls in the s-loop.
//  - 3 independent MFMA accumulators (ah*bh / al*bh / ah*bl): dependent
//    chain 48 -> 16, 3-way MFMA ILP.
//  - bf16 split via pairwise v_perm_b32 packing (~33 VALU/step vs ~52).
// Precision scheme unchanged (K=ah+al, T=Thi+Tlo, drop al*bl ~2^-14 rel).

#define BB 65536
#define FF 8
#define DD 2
#define RR 10
#define UU 32

typedef __attribute__((ext_vector_type(8))) short short8;
typedef __attribute__((ext_vector_type(4))) float f32x4;
typedef __attribute__((ext_vector_type(4))) unsigned int u32x4;

__device__ __forceinline__ unsigned short f2bf_trunc(float x) {
    return (unsigned short)(__builtin_bit_cast(unsigned int, x) >> 16);
}
__device__ __forceinline__ float bf2f(unsigned short h) {
    return __builtin_bit_cast(float, ((unsigned int)h) << 16);
}
__device__ __forceinline__ unsigned int bcu(float x) {
    return __builtin_bit_cast(unsigned int, x);
}
__device__ __forceinline__ float bcf(unsigned int x) {
    return __builtin_bit_cast(float, x);
}

// ---------------- kernel 1: precompute T (one block per unit) ----------------

__global__ __launch_bounds__(256) void precompute_T_fast(
    const float* __restrict__ core11, const float* __restrict__ core12,
    const float* __restrict__ core13, const float* __restrict__ core14,
    const float* __restrict__ core21, const float* __restrict__ core22,
    const float* __restrict__ FM, const float* __restrict__ MT,
    unsigned short* __restrict__ Thi, unsigned short* __restrict__ Tlo)
{
    const int u   = blockIdx.x;    // 0..31
    const int tid = threadIdx.x;   // 0..255

    __shared__ float sC[6][RR * RR * RR];  // staged cores, 24 KB
    __shared__ float sMT[RR * RR];
    __shared__ float sLeaf[FF][2][RR];   // [leaf][basis][r]
    __shared__ float sP[4][4][RR];       // [pair][combo(a_lo + 2*a_hi)][j]
    __shared__ float sQ[2][16][RR];      // [side][combo][j]
    __shared__ float sR1[16][RR];        // Q1 . MT

    // Phase -1: stage cores + MT into LDS, coalesced.
#pragma unroll
    for (int r = 0; r < 4; ++r) {
        const int o = tid + 256 * r;
        if (o < RR * RR * RR) {
            sC[0][o] = core11[o];
            sC[1][o] = core12[o];
            sC[2][o] = core13[o];
            sC[3][o] = core14[o];
            sC[4][o] = core21[o];
            sC[5][o] = core22[o];
        }
    }
    if (tid < RR * RR) sMT[tid] = MT[tid];

    // Phase 0: leaf basis vectors. leaf[f][a][r] = FM[a, r, f, u]
    if (tid < FF * 2 * RR) {             // 160 tasks
        const int f = tid / (2 * RR);
        const int rem = tid % (2 * RR);
        const int a = rem / RR;
        const int r = rem % RR;
        sLeaf[f][a][r] = FM[((a * RR + r) * FF + f) * UU + u];
    }
    __syncthreads();

    // Phase A: level-1 pairs. 4 pairs x 4 combos x RR j = 160 tasks.
    if (tid < 4 * 4 * RR) {
        const int P   = tid / (4 * RR);
        const int rem = tid % (4 * RR);
        const int s   = rem / RR;              // combo: a_lo + 2*a_hi
        const int j   = rem % RR;
        const int fa = 2 * P, fb = 2 * P + 1;
        const int ai = s & 1, bi = s >> 1;
        const float* cp = sC[P];
        float a[RR], b[RR];
#pragma unroll
        for (int i = 0; i < RR; ++i) { a[i] = sLeaf[fa][ai][i]; b[i] = sLeaf[fb][bi][i]; }
        float acc0 = 0.0f, acc1 = 0.0f;
#pragma unroll
        for (int i = 0; i < RR; ++i) {
#pragma unroll
            for (int k = 0; k < RR; ++k) {
                const float w = a[i] * b[k];
                const float c = cp[(i * RR + k) * RR + j];
                if (i & 1) acc1 = fmaf(w, c, acc1);
                else       acc0 = fmaf(w, c, acc0);
            }
        }
        sP[P][s][j] = acc0 + acc1;
    }
    __syncthreads();

    // Phase B: level-2. 2 sides x 16 combos x RR j = 320 tasks.
    for (int t = tid; t < 2 * 16 * RR; t += 256) {
        const int side  = t / (16 * RR);
        const int rem   = t % (16 * RR);
        const int combo = rem / RR;
        const int j     = rem % RR;
        const int pa = side * 2, pb = side * 2 + 1;
        const float* cp = sC[4 + side];
        float a[RR], b[RR];
#pragma unroll
        for (int i = 0; i < RR; ++i) {
            a[i] = sP[pa][combo & 3][i];
            b[i] = sP[pb][combo >> 2][i];
        }
        float acc0 = 0.0f, acc1 = 0.0f;
#pragma unroll
        for (int i = 0; i < RR; ++i) {
#pragma unroll
            for (int k = 0; k < RR; ++k) {
                const float w = a[i] * b[k];
                const float c = cp[(i * RR + k) * RR + j];
                if (i & 1) acc1 = fmaf(w, c, acc1);
                else       acc0 = fmaf(w, c, acc0);
            }
        }
        sQ[side][combo][j] = acc0 + acc1;
    }
    __syncthreads();

    // Phase C: R1[p][j] = sum_i Q1[p][i] * MT[i][j]. 160 tasks.
    if (tid < 16 * RR) {
        const int p = tid / RR;
        const int j = tid % RR;
        float acc = 0.0f;
#pragma unroll
        for (int i = 0; i < RR; ++i)
            acc = fmaf(sQ[0][p][i], sMT[i * RR + j], acc);
        sR1[p][j] = acc;
    }
    __syncthreads();

    // Phase D: T[u][c=q*16+p] = sum_j R1[p][j]*Q2[q][j]; emit bf16 hi/lo split.
    {
        const int c = tid;
        const int p = c & 15, q = c >> 4;
        float acc = 0.0f;
#pragma unroll
        for (int j = 0; j < RR; ++j)
            acc = fmaf(sR1[p][j], sQ[1][q][j], acc);
        const unsigned short h = f2bf_trunc(acc);
        const unsigned short l = f2bf_trunc(acc - bf2f(h));
        Thi[u * 256 + c] = h;
        Tlo[u * 256 + c] = l;
    }
}

// ---------------- kernel 2: batch evaluation via MFMA ----------------
// grid = (512, 2), block = 256 (4 waves). Each wave: 16 units (ubase +
// lane&15 column), 2 iterations x 16 batches. mfma_f32_16x16x32_bf16,
// D: row=(lane>>4)*4+reg -> batch, col=lane&15 -> unit (verified layout).
// K-index algebra: c = s*32 + kb*8 + j  ->  q = 2s+(kb>>1), p=(kb&1)*8+j.

#define NWAVE 2048   // waves per unit-group = gridDim.x * 4

__global__ __launch_bounds__(256, 4) void tree_eval_mfma(
    const float* __restrict__ X,
    const unsigned short* __restrict__ Thi,
    const unsigned short* __restrict__ Tlo,
    float* __restrict__ out)
{
    const int lane  = threadIdx.x & 63;
    const int wid   = threadIdx.x >> 6;                 // 0..3
    const int gw    = blockIdx.x * 4 + wid;             // 0..NWAVE-1
    const int ubase = blockIdx.y * 16;

    const int n  = lane & 15;    // unit column / batch row owner
    const int kb = lane >> 4;    // k-block 0..3

    // ---- hoist the full B-panel into registers (it-loop invariant) ----
    // lane holds T[ubase+n][s*32 + kb*8 + j], j=0..7, for all s.
    const unsigned short* th = Thi + (ubase + n) * 256 + kb * 8;
    const unsigned short* tl = Tlo + (ubase + n) * 256 + kb * 8;
    short8 bh[8], bl[8];
#pragma unroll
    for (int s = 0; s < 8; ++s) {
        bh[s] = *reinterpret_cast<const short8*>(th + s * 32);
        bl[s] = *reinterpret_cast<const short8*>(tl + s * 32);
    }

    const int qpar = kb >> 1;    // parity of w2 index this lane consumes
    const int kpar = kb & 1;     // which half of w1 this lane consumes

    for (int it = 0; it < 2; ++it) {
        const int bbase = (it * NWAVE + gw) * 16;

        // ---- per-lane w build (batch bbase+n; shared across kb groups) ----
        const float* xp = X + (size_t)(bbase + n) * (FF * DD);
        const float4 v0 = *reinterpret_cast<const float4*>(xp + 0);
        const float4 v1 = *reinterpret_cast<const float4*>(xp + 4);
        const float4 v2 = *reinterpret_cast<const float4*>(xp + 8);
        const float4 v3 = *reinterpret_cast<const float4*>(xp + 12);

        float t01[4], t23[4], t45[4], t67[4];
        t01[0] = v0.x * v0.z; t01[1] = v0.y * v0.z; t01[2] = v0.x * v0.w; t01[3] = v0.y * v0.w;
        t23[0] = v1.x * v1.z; t23[1] = v1.y * v1.z; t23[2] = v1.x * v1.w; t23[3] = v1.y * v1.w;
        t45[0] = v2.x * v2.z; t45[1] = v2.y * v2.z; t45[2] = v2.x * v2.w; t45[3] = v2.y * v2.w;
        t67[0] = v3.x * v3.z; t67[1] = v3.y * v3.z; t67[2] = v3.x * v3.w; t67[3] = v3.y * v3.w;

        // w1[p], p = kpar*8+j: w1[p] = t01[j&3] * t23[2*kpar + (j>>2)]
        const float v23_0 = kpar ? t23[2] : t23[0];
        const float v23_1 = kpar ? t23[3] : t23[1];
        float w1own[8];
#pragma unroll
        for (int j = 0; j < 8; ++j)
            w1own[j] = t01[j & 3] * ((j >> 2) ? v23_1 : v23_0);

        // w2[q], q = 2s+qpar: w2[q] = t45[2*(s&1)+qpar] * t67[s>>1]
        const float u45_0 = qpar ? t45[1] : t45[0];
        const float u45_1 = qpar ? t45[3] : t45[2];

        f32x4 acc0 = {0.0f, 0.0f, 0.0f, 0.0f};   // ah*bh
        f32x4 acc1 = {0.0f, 0.0f, 0.0f, 0.0f};   // al*bh
        f32x4 acc2 = {0.0f, 0.0f, 0.0f, 0.0f};   // ah*bl

#pragma unroll
        for (int s = 0; s < 8; ++s) {
            const float w2s = ((s & 1) ? u45_1 : u45_0) * t67[s >> 1];

            // bf16 split of a_j = w1own[j]*w2s, packed pairwise via v_perm.
            u32x4 ahp, alp;
#pragma unroll
            for (int e = 0; e < 4; ++e) {
                const float a0 = w1own[2 * e + 0] * w2s;
                const float a1 = w1own[2 * e + 1] * w2s;
                // hi16(a1):hi16(a0)
                ahp[e] = __builtin_amdgcn_perm(bcu(a1), bcu(a0), 0x07060302u);
                const float r0 = a0 - bcf(bcu(a0) & 0xFFFF0000u);
                const float r1 = a1 - bcf(bcu(a1) & 0xFFFF0000u);
                alp[e] = __builtin_amdgcn_perm(bcu(r1), bcu(r0), 0x07060302u);
            }
            const short8 ah = __builtin_bit_cast(short8, ahp);
            const short8 al = __builtin_bit_cast(short8, alp);

            acc0 = __builtin_amdgcn_mfma_f32_16x16x32_bf16(ah, bh[s], acc0, 0, 0, 0);
            acc1 = __builtin_amdgcn_mfma_f32_16x16x32_bf16(al, bh[s], acc1, 0, 0, 0);
            acc2 = __builtin_amdgcn_mfma_f32_16x16x32_bf16(ah, bl[s], acc2, 0, 0, 0);
        }

        // D: batch = bbase + kb*4 + r, unit = ubase + n
        float* op = out + (size_t)(bbase + kb * 4) * UU + ubase + n;
#pragma unroll
        for (int r = 0; r < 4; ++r)
            op[(size_t)r * UU] = (acc0[r] + acc1[r]) + acc2[r];
    }
}

extern "C" void kernel_launch(void* const* d_in, const int* in_sizes, int n_in,
                              void* d_out, int out_size, void* d_ws, size_t ws_size,
                              hipStream_t stream) {
    const float* X      = (const float*)d_in[0];
    const float* core11 = (const float*)d_in[1];
    const float* core12 = (const float*)d_in[2];
    const float* core13 = (const float*)d_in[3];
    const float* core14 = (const float*)d_in[4];
    const float* core21 = (const float*)d_in[5];
    const float* core22 = (const float*)d_in[6];
    const float* FM     = (const float*)d_in[7];
    const float* MT     = (const float*)d_in[8];
    float* out          = (float*)d_out;

    unsigned short* Thi = (unsigned short*)d_ws;          // 32*256*2 = 16 KB
    unsigned short* Tlo = Thi + UU * 256;                 // +16 KB

    precompute_T_fast<<<dim3(UU), dim3(256), 0, stream>>>(
        core11, core12, core13, core14, core21, core22, FM, MT, Thi, Tlo);

    tree_eval_mfma<<<dim3(512, 2), dim3(256), 0, stream>>>(X, Thi, Tlo, out);
}

// Round 5
// 84.214 us; speedup vs baseline: 1.3583x; 1.0497x over previous
//
#include <hip/hip_runtime.h>

// TensorTree collapsed to multilinear table: out[b,u] = w1(b)^T T_u w2(b),
//   out[b,u] = sum_c K[b][c] * T[u][c],  c = q*16+p,  K[c] = w1[p]*w2[q]
// Round 8: eval regrid. R7 inferred ~16 us vs ~4 us issue model ->
// dispatch-ramp + prologue amortization + register headroom:
//  - grid (512,2)->(256,2), it 2->4: half the workgroups, B-panel
//    prologue (16 loads, 64 VGPRs) amortized over 4 iterations.
//  - __launch_bounds__(256,2): 256-VGPR budget so the full it-unroll can
//    hoist/pipeline X loads across iterations (no spill risk). Occupancy
//    is grid-limited at 2 waves/SIMD anyway (512 blocks x 4 waves / 1024).
//  - numerics bit-identical to R7 (absmax should stay exactly 0.25).
// Precision scheme: K=ah+al, T=Thi+Tlo, 3 MFMA products (al*bh needed:
// dropping it scales error by ~2^9 -> ~100 absmax. Keep all 3.)

#define BB 65536
#define FF 8
#define DD 2
#define RR 10
#define UU 32

typedef __attribute__((ext_vector_type(8))) short short8;
typedef __attribute__((ext_vector_type(4))) float f32x4;
typedef __attribute__((ext_vector_type(4))) unsigned int u32x4;

__device__ __forceinline__ unsigned short f2bf_trunc(float x) {
    return (unsigned short)(__builtin_bit_cast(unsigned int, x) >> 16);
}
__device__ __forceinline__ float bf2f(unsigned short h) {
    return __builtin_bit_cast(float, ((unsigned int)h) << 16);
}
__device__ __forceinline__ unsigned int bcu(float x) {
    return __builtin_bit_cast(unsigned int, x);
}
__device__ __forceinline__ float bcf(unsigned int x) {
    return __builtin_bit_cast(float, x);
}

// ---------------- kernel 1: precompute T (one block per unit) ----------------

__global__ __launch_bounds__(256) void precompute_T_fast(
    const float* __restrict__ core11, const float* __restrict__ core12,
    const float* __restrict__ core13, const float* __restrict__ core14,
    const float* __restrict__ core21, const float* __restrict__ core22,
    const float* __restrict__ FM, const float* __restrict__ MT,
    unsigned short* __restrict__ Thi, unsigned short* __restrict__ Tlo)
{
    const int u   = blockIdx.x;    // 0..31
    const int tid = threadIdx.x;   // 0..255

    __shared__ float sC[6][RR * RR * RR];  // staged cores, 24 KB
    __shared__ float sMT[RR * RR];
    __shared__ float sLeaf[FF][2][RR];   // [leaf][basis][r]
    __shared__ float sP[4][4][RR];       // [pair][combo(a_lo + 2*a_hi)][j]
    __shared__ float sQ[2][16][RR];      // [side][combo][j]
    __shared__ float sR1[16][RR];        // Q1 . MT

    // Phase -1: stage cores + MT into LDS, coalesced.
#pragma unroll
    for (int r = 0; r < 4; ++r) {
        const int o = tid + 256 * r;
        if (o < RR * RR * RR) {
            sC[0][o] = core11[o];
            sC[1][o] = core12[o];
            sC[2][o] = core13[o];
            sC[3][o] = core14[o];
            sC[4][o] = core21[o];
            sC[5][o] = core22[o];
        }
    }
    if (tid < RR * RR) sMT[tid] = MT[tid];

    // Phase 0: leaf basis vectors. leaf[f][a][r] = FM[a, r, f, u]
    if (tid < FF * 2 * RR) {             // 160 tasks
        const int f = tid / (2 * RR);
        const int rem = tid % (2 * RR);
        const int a = rem / RR;
        const int r = rem % RR;
        sLeaf[f][a][r] = FM[((a * RR + r) * FF + f) * UU + u];
    }
    __syncthreads();

    // Phase A: level-1 pairs. 4 pairs x 4 combos x RR j = 160 tasks.
    if (tid < 4 * 4 * RR) {
        const int P   = tid / (4 * RR);
        const int rem = tid % (4 * RR);
        const int s   = rem / RR;              // combo: a_lo + 2*a_hi
        const int j   = rem % RR;
        const int fa = 2 * P, fb = 2 * P + 1;
        const int ai = s & 1, bi = s >> 1;
        const float* cp = sC[P];
        float a[RR], b[RR];
#pragma unroll
        for (int i = 0; i < RR; ++i) { a[i] = sLeaf[fa][ai][i]; b[i] = sLeaf[fb][bi][i]; }
        float acc0 = 0.0f, acc1 = 0.0f;
#pragma unroll
        for (int i = 0; i < RR; ++i) {
#pragma unroll
            for (int k = 0; k < RR; ++k) {
                const float w = a[i] * b[k];
                const float c = cp[(i * RR + k) * RR + j];
                if (i & 1) acc1 = fmaf(w, c, acc1);
                else       acc0 = fmaf(w, c, acc0);
            }
        }
        sP[P][s][j] = acc0 + acc1;
    }
    __syncthreads();

    // Phase B: level-2. 2 sides x 16 combos x RR j = 320 tasks.
    for (int t = tid; t < 2 * 16 * RR; t += 256) {
        const int side  = t / (16 * RR);
        const int rem   = t % (16 * RR);
        const int combo = rem / RR;
        const int j     = rem % RR;
        const int pa = side * 2, pb = side * 2 + 1;
        const float* cp = sC[4 + side];
        float a[RR], b[RR];
#pragma unroll
        for (int i = 0; i < RR; ++i) {
            a[i] = sP[pa][combo & 3][i];
            b[i] = sP[pb][combo >> 2][i];
        }
        float acc0 = 0.0f, acc1 = 0.0f;
#pragma unroll
        for (int i = 0; i < RR; ++i) {
#pragma unroll
            for (int k = 0; k < RR; ++k) {
                const float w = a[i] * b[k];
                const float c = cp[(i * RR + k) * RR + j];
                if (i & 1) acc1 = fmaf(w, c, acc1);
                else       acc0 = fmaf(w, c, acc0);
            }
        }
        sQ[side][combo][j] = acc0 + acc1;
    }
    __syncthreads();

    // Phase C: R1[p][j] = sum_i Q1[p][i] * MT[i][j]. 160 tasks.
    if (tid < 16 * RR) {
        const int p = tid / RR;
        const int j = tid % RR;
        float acc = 0.0f;
#pragma unroll
        for (int i = 0; i < RR; ++i)
            acc = fmaf(sQ[0][p][i], sMT[i * RR + j], acc);
        sR1[p][j] = acc;
    }
    __syncthreads();

    // Phase D: T[u][c=q*16+p] = sum_j R1[p][j]*Q2[q][j]; emit bf16 hi/lo split.
    {
        const int c = tid;
        const int p = c & 15, q = c >> 4;
        float acc = 0.0f;
#pragma unroll
        for (int j = 0; j < RR; ++j)
            acc = fmaf(sR1[p][j], sQ[1][q][j], acc);
        const unsigned short h = f2bf_trunc(acc);
        const unsigned short l = f2bf_trunc(acc - bf2f(h));
        Thi[u * 256 + c] = h;
        Tlo[u * 256 + c] = l;
    }
}

// ---------------- kernel 2: batch evaluation via MFMA ----------------
// grid = (256, 2), block = 256 (4 waves). Each wave: 16 units (ubase +
// lane&15 column), 4 iterations x 16 batches. mfma_f32_16x16x32_bf16,
// D: row=(lane>>4)*4+reg -> batch, col=lane&15 -> unit (verified layout).
// K-index algebra: c = s*32 + kb*8 + j  ->  q = 2s+(kb>>1), p=(kb&1)*8+j.

#define NWAVE 1024   // waves per unit-group = gridDim.x * 4
#define ITER  4

__global__ __launch_bounds__(256, 2) void tree_eval_mfma(
    const float* __restrict__ X,
    const unsigned short* __restrict__ Thi,
    const unsigned short* __restrict__ Tlo,
    float* __restrict__ out)
{
    const int lane  = threadIdx.x & 63;
    const int wid   = threadIdx.x >> 6;                 // 0..3
    const int gw    = blockIdx.x * 4 + wid;             // 0..NWAVE-1
    const int ubase = blockIdx.y * 16;

    const int n  = lane & 15;    // unit column / batch row owner
    const int kb = lane >> 4;    // k-block 0..3

    // ---- hoist the full B-panel into registers (it-loop invariant) ----
    // lane holds T[ubase+n][s*32 + kb*8 + j], j=0..7, for all s.
    const unsigned short* th = Thi + (ubase + n) * 256 + kb * 8;
    const unsigned short* tl = Tlo + (ubase + n) * 256 + kb * 8;
    short8 bh[8], bl[8];
#pragma unroll
    for (int s = 0; s < 8; ++s) {
        bh[s] = *reinterpret_cast<const short8*>(th + s * 32);
        bl[s] = *reinterpret_cast<const short8*>(tl + s * 32);
    }

    const int qpar = kb >> 1;    // parity of w2 index this lane consumes
    const int kpar = kb & 1;     // which half of w1 this lane consumes

#pragma unroll
    for (int it = 0; it < ITER; ++it) {
        const int bbase = (it * NWAVE + gw) * 16;

        // ---- per-lane w build (batch bbase+n; shared across kb groups) ----
        const float* xp = X + (size_t)(bbase + n) * (FF * DD);
        const float4 v0 = *reinterpret_cast<const float4*>(xp + 0);
        const float4 v1 = *reinterpret_cast<const float4*>(xp + 4);
        const float4 v2 = *reinterpret_cast<const float4*>(xp + 8);
        const float4 v3 = *reinterpret_cast<const float4*>(xp + 12);

        float t01[4], t23[4], t45[4], t67[4];
        t01[0] = v0.x * v0.z; t01[1] = v0.y * v0.z; t01[2] = v0.x * v0.w; t01[3] = v0.y * v0.w;
        t23[0] = v1.x * v1.z; t23[1] = v1.y * v1.z; t23[2] = v1.x * v1.w; t23[3] = v1.y * v1.w;
        t45[0] = v2.x * v2.z; t45[1] = v2.y * v2.z; t45[2] = v2.x * v2.w; t45[3] = v2.y * v2.w;
        t67[0] = v3.x * v3.z; t67[1] = v3.y * v3.z; t67[2] = v3.x * v3.w; t67[3] = v3.y * v3.w;

        // w1[p], p = kpar*8+j: w1[p] = t01[j&3] * t23[2*kpar + (j>>2)]
        const float v23_0 = kpar ? t23[2] : t23[0];
        const float v23_1 = kpar ? t23[3] : t23[1];
        float w1own[8];
#pragma unroll
        for (int j = 0; j < 8; ++j)
            w1own[j] = t01[j & 3] * ((j >> 2) ? v23_1 : v23_0);

        // w2[q], q = 2s+qpar: w2[q] = t45[2*(s&1)+qpar] * t67[s>>1]
        const float u45_0 = qpar ? t45[1] : t45[0];
        const float u45_1 = qpar ? t45[3] : t45[2];

        f32x4 acc0 = {0.0f, 0.0f, 0.0f, 0.0f};   // ah*bh
        f32x4 acc1 = {0.0f, 0.0f, 0.0f, 0.0f};   // al*bh
        f32x4 acc2 = {0.0f, 0.0f, 0.0f, 0.0f};   // ah*bl

#pragma unroll
        for (int s = 0; s < 8; ++s) {
            const float w2s = ((s & 1) ? u45_1 : u45_0) * t67[s >> 1];

            // bf16 split of a_j = w1own[j]*w2s, packed pairwise via v_perm.
            u32x4 ahp, alp;
#pragma unroll
            for (int e = 0; e < 4; ++e) {
                const float a0 = w1own[2 * e + 0] * w2s;
                const float a1 = w1own[2 * e + 1] * w2s;
                // hi16(a1):hi16(a0)
                ahp[e] = __builtin_amdgcn_perm(bcu(a1), bcu(a0), 0x07060302u);
                const float r0 = a0 - bcf(bcu(a0) & 0xFFFF0000u);
                const float r1 = a1 - bcf(bcu(a1) & 0xFFFF0000u);
                alp[e] = __builtin_amdgcn_perm(bcu(r1), bcu(r0), 0x07060302u);
            }
            const short8 ah = __builtin_bit_cast(short8, ahp);
            const short8 al = __builtin_bit_cast(short8, alp);

            acc0 = __builtin_amdgcn_mfma_f32_16x16x32_bf16(ah, bh[s], acc0, 0, 0, 0);
            acc1 = __builtin_amdgcn_mfma_f32_16x16x32_bf16(al, bh[s], acc1, 0, 0, 0);
            acc2 = __builtin_amdgcn_mfma_f32_16x16x32_bf16(ah, bl[s], acc2, 0, 0, 0);
        }

        // D: batch = bbase + kb*4 + r, unit = ubase + n
        float* op = out + (size_t)(bbase + kb * 4) * UU + ubase + n;
#pragma unroll
        for (int r = 0; r < 4; ++r)
            op[(size_t)r * UU] = (acc0[r] + acc1[r]) + acc2[r];
    }
}

extern "C" void kernel_launch(void* const* d_in, const int* in_sizes, int n_in,
                              void* d_out, int out_size, void* d_ws, size_t ws_size,
                              hipStream_t stream) {
    const float* X      = (const float*)d_in[0];
    const float* core11 = (const float*)d_in[1];
    const float* core12 = (const float*)d_in[2];
    const float* core13 = (const float*)d_in[3];
    const float* core14 = (const float*)d_in[4];
    const float* core21 = (const float*)d_in[5];
    const float* core22 = (const float*)d_in[6];
    const float* FM     = (const float*)d_in[7];
    const float* MT     = (const float*)d_in[8];
    float* out          = (float*)d_out;

    unsigned short* Thi = (unsigned short*)d_ws;          // 32*256*2 = 16 KB
    unsigned short* Tlo = Thi + UU * 256;                 // +16 KB

    precompute_T_fast<<<dim3(UU), dim3(256), 0, stream>>>(
        core11, core12, core13, core14, core21, core22, FM, MT, Thi, Tlo);

    tree_eval_mfma<<<dim3(256, 2), dim3(256), 0, stream>>>(X, Thi, Tlo, out);
}